// Round 1
// baseline (1713.898 us; speedup 1.0000x reference)
//
#include <hip/hip_runtime.h>

// Problem constants (fixed by setup_inputs)
#define B_   32
#define T_   32
#define NP_  196      // patches per frame
#define C_   768
#define D_   1536     // 2C
#define S_   42       // P + T
#define P_   10       // prompt tokens
#define H_   3        // heads
#define HD_  512      // head dim
#define K_   16       // top-k
#define NS_  500      // MC samples
#define SIGMA_ 0.05f

// ---------------------------------------------------------------- pooling
// feat[b,t,:C] = mean_n x[b,t,n,:]; feat[b,t,C:] = max_n x[b,t,n,:]
// writes into h rows P..S-1
__global__ __launch_bounds__(256) void pool_kernel(const float* __restrict__ x,
                                                   float* __restrict__ h) {
    int bt = blockIdx.x;                 // b*T + t
    int b = bt / T_, t = bt % T_;
    const float* px = x + (size_t)bt * NP_ * C_;
    int c = threadIdx.x;
    float s0 = 0.f, s1 = 0.f, s2 = 0.f;
    float m0 = -INFINITY, m1 = -INFINITY, m2 = -INFINITY;
    for (int n = 0; n < NP_; ++n) {
        const float* r = px + (size_t)n * C_;
        float v0 = r[c], v1 = r[c + 256], v2 = r[c + 512];
        s0 += v0; s1 += v1; s2 += v2;
        m0 = fmaxf(m0, v0); m1 = fmaxf(m1, v1); m2 = fmaxf(m2, v2);
    }
    float* ph = h + (size_t)(b * S_ + P_ + t) * D_;
    const float inv = 1.f / NP_;
    ph[c] = s0 * inv; ph[c + 256] = s1 * inv; ph[c + 512] = s2 * inv;
    ph[C_ + c] = m0; ph[C_ + c + 256] = m1; ph[C_ + c + 512] = m2;
}

// prompt broadcast into h rows 0..P-1
__global__ __launch_bounds__(256) void prompt_fill_kernel(const float* __restrict__ prompt,
                                                          float* __restrict__ h) {
    int gid = blockIdx.x * 256 + threadIdx.x;   // over B*P*D, exact multiple of 256
    int b = gid / (P_ * D_);
    int rem = gid - b * (P_ * D_);
    h[(size_t)(b * S_) * D_ + rem] = prompt[rem];
}

// ---------------------------------------------------------------- layernorm
__global__ __launch_bounds__(256) void ln_kernel(const float* __restrict__ src,
                                                 float* __restrict__ dst,
                                                 const float* __restrict__ g,
                                                 const float* __restrict__ bb) {
    __shared__ float s1[4], s2[4];
    int row = blockIdx.x;
    const float* p = src + (size_t)row * D_;
    float v[6];
    float sum = 0.f, sq = 0.f;
#pragma unroll
    for (int i = 0; i < 6; ++i) {
        float t = p[threadIdx.x + 256 * i];
        v[i] = t; sum += t; sq += t * t;
    }
#pragma unroll
    for (int m = 32; m >= 1; m >>= 1) {
        sum += __shfl_xor(sum, m);
        sq  += __shfl_xor(sq, m);
    }
    if ((threadIdx.x & 63) == 0) { s1[threadIdx.x >> 6] = sum; s2[threadIdx.x >> 6] = sq; }
    __syncthreads();
    sum = s1[0] + s1[1] + s1[2] + s1[3];
    sq  = s2[0] + s2[1] + s2[2] + s2[3];
    float mu = sum * (1.f / D_);
    float rstd = rsqrtf(sq * (1.f / D_) - mu * mu + 1e-5f);
    float* q = dst + (size_t)row * D_;
#pragma unroll
    for (int i = 0; i < 6; ++i) {
        int cc = threadIdx.x + 256 * i;
        q[cc] = (v[i] - mu) * rstd * g[cc] + bb[cc];
    }
}

// ---------------------------------------------------------------- fp32 GEMM
// out[M,N] = (res ? res : 0) + A[M,K] @ W[K,N] + bias[N]
// BM=BN=64, BK=16, 256 threads, 4x4 micro-tile. M%64==0, N%64==0, K%16==0.
#define BM 64
#define BN 64
#define BK 16
__global__ __launch_bounds__(256) void gemm_kernel(const float* __restrict__ A,
                                                   const float* __restrict__ W,
                                                   const float* __restrict__ bias,
                                                   const float* __restrict__ res,
                                                   float* __restrict__ out,
                                                   int M, int Kd, int Nd) {
    __shared__ float As[BK][BM + 4];
    __shared__ float Bs[BK][BN + 4];
    int tid = threadIdx.x;
    int n0 = blockIdx.x * BN;
    int m0 = blockIdx.y * BM;
    int tx = tid & 15, ty = tid >> 4;
    int a_m = tid >> 2;            // 0..63
    int a_k = (tid & 3) << 2;      // 0,4,8,12
    int b_k = tid >> 4;            // 0..15
    int b_n = (tid & 15) << 2;     // 0..60
    float acc[4][4] = {};
    for (int k0 = 0; k0 < Kd; k0 += BK) {
        float4 av = *reinterpret_cast<const float4*>(&A[(size_t)(m0 + a_m) * Kd + k0 + a_k]);
        As[a_k + 0][a_m] = av.x;
        As[a_k + 1][a_m] = av.y;
        As[a_k + 2][a_m] = av.z;
        As[a_k + 3][a_m] = av.w;
        float4 bv = *reinterpret_cast<const float4*>(&W[(size_t)(k0 + b_k) * Nd + n0 + b_n]);
        *reinterpret_cast<float4*>(&Bs[b_k][b_n]) = bv;
        __syncthreads();
#pragma unroll
        for (int kk = 0; kk < BK; ++kk) {
            float a4[4], b4[4];
#pragma unroll
            for (int i = 0; i < 4; ++i) a4[i] = As[kk][ty * 4 + i];
#pragma unroll
            for (int j = 0; j < 4; ++j) b4[j] = Bs[kk][tx * 4 + j];
#pragma unroll
            for (int i = 0; i < 4; ++i)
#pragma unroll
                for (int j = 0; j < 4; ++j)
                    acc[i][j] += a4[i] * b4[j];
        }
        __syncthreads();
    }
#pragma unroll
    for (int i = 0; i < 4; ++i) {
        int m = m0 + ty * 4 + i;
        int n = n0 + tx * 4;
        float4 o;
        float* po = &out[(size_t)m * Nd + n];
        const float* pr = res ? &res[(size_t)m * Nd + n] : nullptr;
        o.x = acc[i][0] + bias[n + 0] + (pr ? pr[0] : 0.f);
        o.y = acc[i][1] + bias[n + 1] + (pr ? pr[1] : 0.f);
        o.z = acc[i][2] + bias[n + 2] + (pr ? pr[2] : 0.f);
        o.w = acc[i][3] + bias[n + 3] + (pr ? pr[3] : 0.f);
        *reinterpret_cast<float4*>(po) = o;
    }
}

// ---------------------------------------------------------------- attention
// one wave per (b,h,i): scores over j=0..S-1, softmax, PV. qkv row layout:
// [3][H][HD] per (b,s), row pitch 3*D.
__global__ __launch_bounds__(64) void attn_kernel(const float* __restrict__ qkv,
                                                  float* __restrict__ obuf) {
    int bid = blockIdx.x;
    int i = bid % S_;
    int h = (bid / S_) % H_;
    int b = bid / (S_ * H_);
    int lane = threadIdx.x;
    const float scale = 0.04419417382415922f;  // 512^-0.5
    size_t rq = (size_t)(b * S_ + i) * (3 * D_) + h * HD_;
    float q[8];
#pragma unroll
    for (int r = 0; r < 8; ++r) q[r] = qkv[rq + lane + 64 * r] * scale;
    float sc = -INFINITY;
    for (int j = 0; j < S_; ++j) {
        size_t rk = (size_t)(b * S_ + j) * (3 * D_) + D_ + h * HD_;
        float p = 0.f;
#pragma unroll
        for (int r = 0; r < 8; ++r) p += q[r] * qkv[rk + lane + 64 * r];
#pragma unroll
        for (int m = 32; m >= 1; m >>= 1) p += __shfl_xor(p, m);
        if (lane == j) sc = p;
    }
    float mx = sc;
#pragma unroll
    for (int m = 32; m >= 1; m >>= 1) mx = fmaxf(mx, __shfl_xor(mx, m));
    float e = (lane < S_) ? expf(sc - mx) : 0.f;
    float sum = e;
#pragma unroll
    for (int m = 32; m >= 1; m >>= 1) sum += __shfl_xor(sum, m);
    float a = e / sum;
    float o[8] = {};
    for (int j = 0; j < S_; ++j) {
        float av = __shfl(a, j);
        size_t rv = (size_t)(b * S_ + j) * (3 * D_) + 2 * D_ + h * HD_;
#pragma unroll
        for (int r = 0; r < 8; ++r) o[r] += av * qkv[rv + lane + 64 * r];
    }
    size_t ro = (size_t)(b * S_ + i) * D_ + h * HD_;
#pragma unroll
    for (int r = 0; r < 8; ++r) obuf[ro + lane + 64 * r] = o[r];
}

// ---------------------------------------------------------------- scores
__global__ __launch_bounds__(256) void score_kernel(const float* __restrict__ h,
                                                    const float* __restrict__ sw,
                                                    const float* __restrict__ sb,
                                                    float* __restrict__ raw) {
    __shared__ float s1[4];
    int bt = blockIdx.x;                  // b*T + t
    int b = bt / T_, t = bt % T_;
    const float* p = h + (size_t)(b * S_ + P_ + t) * D_;
    float sum = 0.f;
#pragma unroll
    for (int i = 0; i < 6; ++i) {
        int c = threadIdx.x + 256 * i;
        sum += p[c] * sw[c];
    }
#pragma unroll
    for (int m = 32; m >= 1; m >>= 1) sum += __shfl_xor(sum, m);
    if ((threadIdx.x & 63) == 0) s1[threadIdx.x >> 6] = sum;
    __syncthreads();
    if (threadIdx.x == 0) raw[bt] = s1[0] + s1[1] + s1[2] + s1[3] + sb[0];
}

__global__ __launch_bounds__(64) void minmax_kernel(const float* __restrict__ raw,
                                                    float* __restrict__ norm) {
    int b = blockIdx.x;
    int lane = threadIdx.x;
    float v = raw[b * T_ + (lane & 31)];
    float lo = v, hi = v;
#pragma unroll
    for (int m = 32; m >= 1; m >>= 1) {
        lo = fminf(lo, __shfl_xor(lo, m));
        hi = fmaxf(hi, __shfl_xor(hi, m));
    }
    if (lane < T_) norm[b * T_ + lane] = (v - lo) / (hi - lo + 1e-5f);
}

// ---------------------------------------------------------------- MC top-k
// one thread per (b, sample): exact jax.lax.top_k rank semantics
// (ties broken toward lower index), indices sorted ascending.
__global__ __launch_bounds__(256) void topk_kernel(const float* __restrict__ scores,
                                                   const float* __restrict__ noise,
                                                   float* __restrict__ cnt) {
    int gid = blockIdx.x * 256 + threadIdx.x;
    if (gid >= B_ * NS_) return;
    int b = gid / NS_, s = gid % NS_;
    const float* sc = scores + b * T_;
    const float* nz = noise + ((size_t)b * NS_ + s) * T_;
    float p[T_];
#pragma unroll
    for (int t = 0; t < T_; ++t) p[t] = sc[t] + nz[t] * SIGMA_;
    int k = 0;
#pragma unroll
    for (int t = 0; t < T_; ++t) {
        int r = 0;
#pragma unroll
        for (int u = 0; u < T_; ++u)
            r += (p[u] > p[t]) || ((p[u] == p[t]) && (u < t));
        if (r < K_) {
            atomicAdd(&cnt[(b * K_ + k) * T_ + t], 1.0f);
            ++k;
        }
    }
}

// ---------------------------------------------------------------- gather
// out[b, k*N+n, :] = (1/NS) * sum_t cnt[b,k,t] * x[b, t*N+n, :]
__global__ __launch_bounds__(256) void gather_kernel(const float* __restrict__ cnt,
                                                     const float* __restrict__ x,
                                                     float* __restrict__ out) {
    int bid = blockIdx.x;
    int n = bid % NP_;
    int k = (bid / NP_) % K_;
    int b = bid / (NP_ * K_);
    __shared__ float w[T_];
    if (threadIdx.x < T_) w[threadIdx.x] = cnt[(b * K_ + k) * T_ + threadIdx.x] * (1.f / NS_);
    __syncthreads();
    float a0 = 0.f, a1 = 0.f, a2 = 0.f;
    int c = threadIdx.x;
    for (int t = 0; t < T_; ++t) {
        float wt = w[t];
        if (wt != 0.f) {
            const float* px = x + ((size_t)(b * T_ + t) * NP_ + n) * C_;
            a0 += wt * px[c];
            a1 += wt * px[c + 256];
            a2 += wt * px[c + 512];
        }
    }
    float* po = out + ((size_t)(b * K_ + k) * NP_ + n) * C_;
    po[c] = a0; po[c + 256] = a1; po[c + 512] = a2;
}

// ---------------------------------------------------------------- launch
extern "C" void kernel_launch(void* const* d_in, const int* in_sizes, int n_in,
                              void* d_out, int out_size, void* d_ws, size_t ws_size,
                              hipStream_t stream) {
    const float* x       = (const float*)d_in[0];
    const float* noise   = (const float*)d_in[1];
    const float* prompt  = (const float*)d_in[2];
    const float* ln1_g   = (const float*)d_in[3];
    const float* ln1_b   = (const float*)d_in[4];
    const float* qkv_w   = (const float*)d_in[5];
    const float* qkv_b   = (const float*)d_in[6];
    const float* proj_w  = (const float*)d_in[7];
    const float* proj_b  = (const float*)d_in[8];
    const float* ln2_g   = (const float*)d_in[9];
    const float* ln2_b   = (const float*)d_in[10];
    const float* fc_w    = (const float*)d_in[11];
    const float* fc_b    = (const float*)d_in[12];
    const float* score_w = (const float*)d_in[13];
    const float* score_b = (const float*)d_in[14];
    float* out = (float*)d_out;

    // workspace layout (floats); total ~39.5 MB
    const size_t HS = (size_t)B_ * S_ * D_;          // 2,064,384
    float* h      = (float*)d_ws;
    float* z      = h + HS;                          // ln out / attn out (reused)
    float* qkv    = z + HS;                          // 3*HS
    float* sraw   = qkv + 3 * HS;                    // B*T
    float* snorm  = sraw + B_ * T_;                  // B*T
    float* cnt    = snorm + B_ * T_;                 // B*K*T

    hipMemsetAsync(cnt, 0, (size_t)B_ * K_ * T_ * sizeof(float), stream);

    pool_kernel<<<B_ * T_, 256, 0, stream>>>(x, h);
    prompt_fill_kernel<<<(B_ * P_ * D_) / 256, 256, 0, stream>>>(prompt, h);

    ln_kernel<<<B_ * S_, 256, 0, stream>>>(h, z, ln1_g, ln1_b);
    gemm_kernel<<<dim3((3 * D_) / BN, (B_ * S_) / BM), 256, 0, stream>>>(
        z, qkv_w, qkv_b, nullptr, qkv, B_ * S_, D_, 3 * D_);
    attn_kernel<<<B_ * H_ * S_, 64, 0, stream>>>(qkv, z);
    gemm_kernel<<<dim3(D_ / BN, (B_ * S_) / BM), 256, 0, stream>>>(
        z, proj_w, proj_b, h, h, B_ * S_, D_, D_);
    ln_kernel<<<B_ * S_, 256, 0, stream>>>(h, z, ln2_g, ln2_b);
    gemm_kernel<<<dim3(D_ / BN, (B_ * S_) / BM), 256, 0, stream>>>(
        z, fc_w, fc_b, h, h, B_ * S_, D_, D_);

    score_kernel<<<B_ * T_, 256, 0, stream>>>(h, score_w, score_b, sraw);
    minmax_kernel<<<B_, 64, 0, stream>>>(sraw, snorm);
    topk_kernel<<<(B_ * NS_ + 255) / 256, 256, 0, stream>>>(snorm, noise, cnt);
    gather_kernel<<<B_ * K_ * NP_, 256, 0, stream>>>(cnt, x, out);
}